// Round 5
// baseline (1274.325 us; speedup 1.0000x reference)
//
#include <hip/hip_runtime.h>
#include <hip/hip_bf16.h>
#include <math.h>

// Problem dims (DAGNN_14594298872388)
#define NN     100000   // nodes
#define INDIM  500
#define HID    256
#define NCLASS 50
#define KHOPS  10
#define KPAD   512      // INDIM padded to multiple of 32 for MFMA
#define CPAD   64       // NCLASS padded (32 packed bf16 pairs per node row)

static inline size_t roundup256(size_t x) { return (x + 255) & ~(size_t)255; }

typedef __attribute__((ext_vector_type(8))) short bf16x8;   // 8 bf16 = 4 VGPRs
typedef __attribute__((ext_vector_type(4))) float f32x4;    // MFMA acc
typedef __attribute__((ext_vector_type(4))) short short4v;

__device__ inline short f2bf(float f) {      // fp32 -> bf16, round-nearest-even
    union { float f; unsigned u; } v; v.f = f;
    unsigned r = v.u + 0x7FFFu + ((v.u >> 16) & 1u);
    return (short)(r >> 16);
}
__device__ inline float bflo(unsigned u) {   // low bf16 of packed pair -> fp32
    union { unsigned u; float f; } v; v.u = u << 16; return v.f;
}
__device__ inline float bfhi(unsigned u) {   // high bf16 of packed pair -> fp32
    union { unsigned u; float f; } v; v.u = u & 0xFFFF0000u; return v.f;
}
__device__ inline unsigned packbf(float a, float b) {
    return (unsigned)(unsigned short)f2bf(a) | ((unsigned)(unsigned short)f2bf(b) << 16);
}

// ---------------------------------------------------------------------------
// prep: zero counters, degree, norm, scan, CSR fill
// ---------------------------------------------------------------------------
__global__ void dagnn_zero2(int* __restrict__ a, int* __restrict__ b, int n) {
    int i = blockIdx.x * blockDim.x + threadIdx.x;
    if (i < n) { a[i] = 0; b[i] = 0; }
}

__global__ void dagnn_deg(const int* __restrict__ dst, int* __restrict__ degi, int E) {
    int e = blockIdx.x * blockDim.x + threadIdx.x;
    if (e < E) atomicAdd(&degi[dst[e]], 1);
}

__global__ void dagnn_norm(const int* __restrict__ degi, float* __restrict__ nrm, int n) {
    int i = blockIdx.x * blockDim.x + threadIdx.x;
    if (i < n) nrm[i] = rsqrtf((float)degi[i]);   // deg >= 1 (self loop)
}

__global__ void dagnn_scan(const int* __restrict__ degi, int* __restrict__ rowptr, int n) {
    __shared__ int wsum[16];
    __shared__ int carry_s;
    const int tid  = threadIdx.x;        // 1024
    const int lane = tid & 63;
    const int wid  = tid >> 6;
    if (tid == 0) carry_s = 0;
    __syncthreads();
    for (int base = 0; base < n; base += 4096) {
        int i0 = base + tid * 4;
        int v0 = (i0 + 0 < n) ? degi[i0 + 0] : 0;
        int v1 = (i0 + 1 < n) ? degi[i0 + 1] : 0;
        int v2 = (i0 + 2 < n) ? degi[i0 + 2] : 0;
        int v3 = (i0 + 3 < n) ? degi[i0 + 3] : 0;
        int tsum = v0 + v1 + v2 + v3;
        int x = tsum;
        #pragma unroll
        for (int off = 1; off < 64; off <<= 1) {
            int t = __shfl_up(x, off);
            if (lane >= off) x += t;
        }
        if (lane == 63) wsum[wid] = x;
        __syncthreads();
        if (tid == 0) {
            int run = carry_s;
            #pragma unroll
            for (int w = 0; w < 16; ++w) { int t = wsum[w]; wsum[w] = run; run += t; }
            carry_s = run;
        }
        __syncthreads();
        int texcl = wsum[wid] + (x - tsum);
        if (i0 + 0 < n) rowptr[i0 + 0] = texcl;
        if (i0 + 1 < n) rowptr[i0 + 1] = texcl + v0;
        if (i0 + 2 < n) rowptr[i0 + 2] = texcl + v0 + v1;
        if (i0 + 3 < n) rowptr[i0 + 3] = texcl + v0 + v1 + v2;
        __syncthreads();
    }
    if (tid == 0) rowptr[n] = carry_s;
}

__global__ void dagnn_fill(const int* __restrict__ src, const int* __restrict__ dst,
                           const int* __restrict__ rowptr, int* __restrict__ fillc,
                           int* __restrict__ colidx, int E) {
    int e = blockIdx.x * blockDim.x + threadIdx.x;
    if (e >= E) return;
    int d = dst[e];
    int pos = rowptr[d] + atomicAdd(&fillc[d], 1);
    colidx[pos] = src[e];
}

// ---------------------------------------------------------------------------
// W1 [500][256] fp32 -> W1t [256][512] bf16 (transposed, zero-padded K)
// ---------------------------------------------------------------------------
__global__ void dagnn_w1t(const float* __restrict__ W1, short* __restrict__ W1t) {
    int idx = blockIdx.x * 256 + threadIdx.x;   // 256*512 = 131072
    if (idx >= HID * KPAD) return;
    int n = idx >> 9;         // 0..255
    int k = idx & (KPAD - 1); // 0..511
    float v = (k < INDIM) ? W1[(size_t)k * HID + n] : 0.f;
    W1t[idx] = f2bf(v);
}

// ---------------------------------------------------------------------------
// W2 [256][50] fp32 -> W2t [64][256] bf16 (transposed, zero-padded N)
// ---------------------------------------------------------------------------
__global__ void dagnn_w2t(const float* __restrict__ W2, short* __restrict__ W2t) {
    int idx = blockIdx.x * 256 + threadIdx.x;   // 64*256 = 16384
    if (idx >= CPAD * HID) return;
    int n = idx >> 8;         // 0..63
    int k = idx & 255;        // 0..255
    float v = (n < NCLASS) ? W2[(size_t)k * NCLASS + n] : 0.f;
    W2t[idx] = f2bf(v);
}

// sg4[q] = (s[4q], s[4q+1], s[4q+2], s[4q+3]) zero-padded; 16 entries
__global__ void dagnn_sgate4(const float* __restrict__ svec, float4* __restrict__ sg) {
    int q = threadIdx.x;
    if (q < 16) {
        float4 g;
        g.x = (4 * q + 0 < NCLASS) ? svec[4 * q + 0] : 0.f;
        g.y = (4 * q + 1 < NCLASS) ? svec[4 * q + 1] : 0.f;
        g.z = (4 * q + 2 < NCLASS) ? svec[4 * q + 2] : 0.f;
        g.w = (4 * q + 3 < NCLASS) ? svec[4 * q + 3] : 0.f;
        sg[q] = g;
    }
}

// ---------------------------------------------------------------------------
// GEMM1 (MFMA bf16): hid = relu(feats @ W1 + b1), bf16 out
// block = 256 threads (4 waves); tile 128(M) x 128(N); BK=32; K=512 (padded)
// grid = (ceil(M/128), 2). Smaller tile -> ~2x more blocks/CU so the
// vmcnt(0)-before-barrier drains of different blocks overlap.
// ---------------------------------------------------------------------------
#define G1_STRIDE 40   // LDS row stride in bf16 units (80 B)
__global__ __launch_bounds__(256) void dagnn_gemm1_mfma(
        const float* __restrict__ A, const short* __restrict__ Bt,
        const float* __restrict__ bias, short* __restrict__ C, int M) {
    __shared__ __align__(16) short As[128 * G1_STRIDE];  // 10 KB
    __shared__ __align__(16) short Bs[128 * G1_STRIDE];  // 10 KB

    const int tid  = threadIdx.x;
    const int lane = tid & 63;
    const int wid  = tid >> 6;              // 0..3
    const int l16  = lane & 15;
    const int quad = lane >> 4;             // 0..3
    const int m_off = (wid & 1) * 64;
    const int n_off = (wid >> 1) * 64;
    const int row0  = blockIdx.x * 128;
    const int col0  = blockIdx.y * 128;

    // staging slot decode: A = 4 slots/thread (128 rows x 8 segs of 4 f32),
    //                      B = 2 slots/thread (128 rows x 4 segs of 8 bf16)
    int am[4], aseg[4], bn[2], bseg[2];
    #pragma unroll
    for (int it = 0; it < 4; ++it) {
        int slot = tid + it * 256;          // 0..1023
        am[it] = slot >> 3; aseg[it] = slot & 7;
    }
    #pragma unroll
    for (int it = 0; it < 2; ++it) {
        int slot = tid + it * 256;          // 0..511
        bn[it] = slot >> 2; bseg[it] = slot & 3;
    }

    float4 ra[4]; bf16x8 rb[2];

    #define LOAD_TILE(k0)                                                     \
        _Pragma("unroll")                                                     \
        for (int it = 0; it < 4; ++it) {                                      \
            int gm = row0 + am[it];                                           \
            int gk = (k0) + aseg[it] * 4;                                     \
            float4 f = {0.f, 0.f, 0.f, 0.f};                                  \
            if (gm < M) {                                                     \
                const float* ap = A + (size_t)gm * INDIM + gk;                \
                if (gk + 3 < INDIM) f = *(const float4*)ap;                   \
                else {                                                        \
                    if (gk + 0 < INDIM) f.x = ap[0];                          \
                    if (gk + 1 < INDIM) f.y = ap[1];                          \
                    if (gk + 2 < INDIM) f.z = ap[2];                          \
                    if (gk + 3 < INDIM) f.w = ap[3];                          \
                }                                                             \
            }                                                                 \
            ra[it] = f;                                                       \
        }                                                                     \
        _Pragma("unroll")                                                     \
        for (int it = 0; it < 2; ++it)                                        \
            rb[it] = *(const bf16x8*)(Bt + (size_t)(col0 + bn[it]) * KPAD     \
                                      + (k0) + bseg[it] * 8);

    #define STORE_TILE()                                                      \
        _Pragma("unroll")                                                     \
        for (int it = 0; it < 4; ++it) {                                      \
            short4v sv;                                                       \
            sv.x = f2bf(ra[it].x); sv.y = f2bf(ra[it].y);                     \
            sv.z = f2bf(ra[it].z); sv.w = f2bf(ra[it].w);                     \
            *(short4v*)&As[am[it] * G1_STRIDE + aseg[it] * 4] = sv;           \
        }                                                                     \
        _Pragma("unroll")                                                     \
        for (int it = 0; it < 2; ++it)                                        \
            *(bf16x8*)&Bs[bn[it] * G1_STRIDE + bseg[it] * 8] = rb[it];

    f32x4 acc[4][4] = {};

    LOAD_TILE(0)
    STORE_TILE()
    __syncthreads();

    for (int ks = 0; ks < KPAD / 32; ++ks) {
        if (ks + 1 < KPAD / 32) { LOAD_TILE((ks + 1) * 32) }  // prefetch

        bf16x8 af[4], bfr[4];
        #pragma unroll
        for (int mt = 0; mt < 4; ++mt)
            af[mt] = *(const bf16x8*)&As[(m_off + mt * 16 + l16) * G1_STRIDE + quad * 8];
        #pragma unroll
        for (int nt = 0; nt < 4; ++nt)
            bfr[nt] = *(const bf16x8*)&Bs[(n_off + nt * 16 + l16) * G1_STRIDE + quad * 8];
        #pragma unroll
        for (int mt = 0; mt < 4; ++mt)
            #pragma unroll
            for (int nt = 0; nt < 4; ++nt)
                acc[mt][nt] = __builtin_amdgcn_mfma_f32_16x16x32_bf16(
                                  af[mt], bfr[nt], acc[mt][nt], 0, 0, 0);
        __syncthreads();                      // all waves done reading LDS
        if (ks + 1 < KPAD / 32) { STORE_TILE() }
        __syncthreads();
    }
    #undef LOAD_TILE
    #undef STORE_TILE

    // epilogue: bias + relu -> bf16; C/D layout col=lane&15, row=quad*4+reg
    #pragma unroll
    for (int nt = 0; nt < 4; ++nt) {
        int gc = col0 + n_off + nt * 16 + l16;
        float bb = bias[gc];
        #pragma unroll
        for (int mt = 0; mt < 4; ++mt) {
            #pragma unroll
            for (int r = 0; r < 4; ++r) {
                int gm = row0 + m_off + mt * 16 + quad * 4 + r;
                if (gm < M) {
                    float v = acc[mt][nt][r] + bb;
                    C[(size_t)gm * HID + gc] = f2bf(v > 0.f ? v : 0.f);
                }
            }
        }
    }
}

// ---------------------------------------------------------------------------
// GEMM2 (MFMA) + gate epilogue:
//   x = hid(bf16) @ W2 + b2 ; hs0 = packed-bf16(x*nrm) ; out = sigmoid(x.s)*x
// block = 256 threads (4 waves); tile 128(M) x 64(N); K=256, BK=64
// ---------------------------------------------------------------------------
#define A2_STRIDE 72
#define B2_STRIDE 264
__global__ __launch_bounds__(256) void dagnn_mlp2_mfma(
        const short* __restrict__ hid, const short* __restrict__ W2t,
        const float* __restrict__ b2, const float* __restrict__ svec,
        const float* __restrict__ nrm,
        unsigned* __restrict__ hs0, float* __restrict__ out, int M) {
    __shared__ __align__(16) short As[128 * A2_STRIDE];
    __shared__ __align__(16) short Bs[CPAD * B2_STRIDE];

    const int tid  = threadIdx.x;
    const int lane = tid & 63;
    const int wid  = tid >> 6;              // 0..3
    const int l16  = lane & 15;
    const int quad = lane >> 4;
    const int m_off = wid * 32;
    const int row0  = blockIdx.x * 128;

    // stage all of W2t (64 x 256) into LDS once
    #pragma unroll
    for (int it = 0; it < 8; ++it) {
        int slot = tid + it * 256;          // 0..2047
        int n   = slot >> 5;                // 0..63
        int seg = slot & 31;                // 8 bf16 each
        bf16x8 b = *(const bf16x8*)(W2t + (size_t)n * HID + seg * 8);
        *(bf16x8*)&Bs[n * B2_STRIDE + seg * 8] = b;
    }

    f32x4 acc[2][4] = {};

    for (int ks = 0; ks < HID / 64; ++ks) {     // 4 iterations, BK=64
        const int k0 = ks * 64;
        #pragma unroll
        for (int it = 0; it < 4; ++it) {
            int slot = tid + it * 256;      // 0..1023
            int m   = slot >> 3;            // 0..127
            int seg = slot & 7;             // 8 bf16 each
            int gm  = row0 + m;
            bf16x8 v = {};
            if (gm < M) v = *(const bf16x8*)(hid + (size_t)gm * HID + k0 + seg * 8);
            *(bf16x8*)&As[m * A2_STRIDE + seg * 8] = v;
        }
        __syncthreads();

        #pragma unroll
        for (int ksub = 0; ksub < 2; ++ksub) {
            bf16x8 af[2], bfr[4];
            #pragma unroll
            for (int mt = 0; mt < 2; ++mt)
                af[mt] = *(const bf16x8*)&As[(m_off + mt * 16 + l16) * A2_STRIDE
                                             + ksub * 32 + quad * 8];
            #pragma unroll
            for (int nt = 0; nt < 4; ++nt)
                bfr[nt] = *(const bf16x8*)&Bs[(nt * 16 + l16) * B2_STRIDE
                                              + k0 + ksub * 32 + quad * 8];
            #pragma unroll
            for (int mt = 0; mt < 2; ++mt)
                #pragma unroll
                for (int nt = 0; nt < 4; ++nt)
                    acc[mt][nt] = __builtin_amdgcn_mfma_f32_16x16x32_bf16(
                                      af[mt], bfr[nt], acc[mt][nt], 0, 0, 0);
        }
        __syncthreads();
    }

    float b2v[4], ssv[4];
    #pragma unroll
    for (int nt = 0; nt < 4; ++nt) {
        int gc = nt * 16 + l16;
        b2v[nt] = (gc < NCLASS) ? b2[gc]   : 0.f;
        ssv[nt] = (gc < NCLASS) ? svec[gc] : 0.f;
    }
    #pragma unroll
    for (int mt = 0; mt < 2; ++mt) {
        #pragma unroll
        for (int r = 0; r < 4; ++r) {
            int gm = row0 + m_off + mt * 16 + quad * 4 + r;
            float xv[4], q = 0.f;
            #pragma unroll
            for (int nt = 0; nt < 4; ++nt) {
                xv[nt] = acc[mt][nt][r] + b2v[nt];
                q += xv[nt] * ssv[nt];
            }
            #pragma unroll
            for (int off = 1; off < 16; off <<= 1) q += __shfl_xor(q, off);
            float S = 1.f / (1.f + __expf(-q));
            float nd = (gm < M) ? nrm[gm] : 0.f;
            #pragma unroll
            for (int nt = 0; nt < 4; ++nt) {
                int gc = nt * 16 + l16;
                float hv = xv[nt] * nd;
                float hp = __shfl_xor(hv, 1);     // partner lane's value
                if (gm < M) {
                    if (!(l16 & 1))               // even lane packs (gc, gc+1)
                        hs0[(size_t)gm * 32 + nt * 8 + (l16 >> 1)] = packbf(hv, hp);
                    if (gc < NCLASS) out[(size_t)gm * NCLASS + gc] = S * xv[nt];
                }
            }
        }
    }
}

// ---------------------------------------------------------------------------
// propagation hop v5 (packed bf16 rows, 128 B/node), quarter-wave per edge:
//   16 lanes x uint2 (8 B) cover one row -> 4 edges per load instruction,
//   8 edges in flight per wave.
//   r[d]       = nrm[d] * sum_{s in N(d)} hs[s]       (fp32 accumulate)
//   hs_next[d] = packed-bf16(r * nrm[d])
//   out[d]    += sigmoid(r . s) * r
// ---------------------------------------------------------------------------
__global__ __launch_bounds__(256) void dagnn_prop5(
        const unsigned* __restrict__ hs, const float* __restrict__ nrm,
        const int* __restrict__ rowptr, const int* __restrict__ colidx,
        const float4* __restrict__ sg4, unsigned* __restrict__ hs_next,
        float* __restrict__ out, int M, int write_next) {
    const int lane = threadIdx.x & 63;
    const int wid  = threadIdx.x >> 6;
    const int d    = blockIdx.x * 4 + wid;
    if (d >= M) return;
    const int sub = lane >> 4;          // edge slot 0..3
    const int q   = lane & 15;          // channel quad: ch 4q..4q+3
    const int beg = rowptr[d], end = rowptr[d + 1];

    float a0 = 0.f, a1 = 0.f, a2 = 0.f, a3 = 0.f;
    for (int e = beg; e < end; e += 8) {
        int i0 = e + sub;
        int i1 = e + 4 + sub;
        int s0 = colidx[(i0 < end) ? i0 : (end - 1)];
        int s1 = colidx[(i1 < end) ? i1 : (end - 1)];
        uint2 u0 = *(const uint2*)&hs[(size_t)s0 * 32 + q * 2];
        uint2 u1 = *(const uint2*)&hs[(size_t)s1 * 32 + q * 2];
        if (i0 < end) {
            a0 += bflo(u0.x); a1 += bfhi(u0.x);
            a2 += bflo(u0.y); a3 += bfhi(u0.y);
        }
        if (i1 < end) {
            a0 += bflo(u1.x); a1 += bfhi(u1.x);
            a2 += bflo(u1.y); a3 += bfhi(u1.y);
        }
    }
    // combine the 4 edge-slot partials (lanes differing in bits 4,5)
    a0 += __shfl_xor(a0, 16); a0 += __shfl_xor(a0, 32);
    a1 += __shfl_xor(a1, 16); a1 += __shfl_xor(a1, 32);
    a2 += __shfl_xor(a2, 16); a2 += __shfl_xor(a2, 32);
    a3 += __shfl_xor(a3, 16); a3 += __shfl_xor(a3, 32);

    float nd = nrm[d];
    float r0 = a0 * nd, r1 = a1 * nd, r2 = a2 * nd, r3 = a3 * nd;
    float4 g = sg4[q];
    float p = r0 * g.x + r1 * g.y + r2 * g.z + r3 * g.w;
    #pragma unroll
    for (int off = 1; off < 16; off <<= 1) p += __shfl_xor(p, off);
    float S = 1.f / (1.f + __expf(-p));

    if (sub == 0) {
        if (write_next) {
            uint2 w;
            w.x = packbf(r0 * nd, r1 * nd);
            w.y = packbf(r2 * nd, r3 * nd);
            *(uint2*)&hs_next[(size_t)d * 32 + q * 2] = w;
        }
        int ch = 4 * q;
        float* op = out + (size_t)d * NCLASS + ch;
        if (ch + 1 < NCLASS) {               // q <= 12: ch, ch+1 valid
            float2 o = *(float2*)op;
            o.x += S * r0; o.y += S * r1;
            *(float2*)op = o;
        }
        if (ch + 3 < NCLASS) {               // q <= 11: ch+2, ch+3 valid
            float2 o = *(float2*)(op + 2);
            o.x += S * r2; o.y += S * r3;
            *(float2*)(op + 2) = o;
        }
    }
}

// ---------------------------------------------------------------------------
extern "C" void kernel_launch(void* const* d_in, const int* in_sizes, int n_in,
                              void* d_out, int out_size, void* d_ws, size_t ws_size,
                              hipStream_t stream) {
    const float* feats = (const float*)d_in[0];
    const float* W1    = (const float*)d_in[1];
    const float* b1    = (const float*)d_in[2];
    const float* W2    = (const float*)d_in[3];
    const float* b2    = (const float*)d_in[4];
    const float* svec  = (const float*)d_in[5];
    const int*   src   = (const int*)d_in[6];
    const int*   dst   = (const int*)d_in[7];
    float* out = (float*)d_out;

    const int M = in_sizes[0] / INDIM;    // 100000
    const int E = in_sizes[6];            // 1600000

    // workspace carve-up
    char* p = (char*)d_ws;
    size_t off = 0;
    short*    hid   = (short*)   (p + off); off += roundup256((size_t)M * HID * 2);
    unsigned* hsA   = (unsigned*)(p + off); off += roundup256((size_t)M * 32 * 4);
    unsigned* hsB   = (unsigned*)(p + off); off += roundup256((size_t)M * 32 * 4);
    short*    W1t   = (short*)   (p + off); off += roundup256((size_t)HID * KPAD * 2);
    short*    W2t   = (short*)   (p + off); off += roundup256((size_t)CPAD * HID * 2);
    float4*   sg4   = (float4*)  (p + off); off += roundup256(16 * sizeof(float4));
    int*      degi  = (int*)     (p + off); off += roundup256((size_t)M * 4);
    float*    nrm   = (float*)   (p + off); off += roundup256((size_t)M * 4);
    int*      rowptr= (int*)     (p + off); off += roundup256((size_t)(M + 1) * 4);
    int*      fillc = (int*)     (p + off); off += roundup256((size_t)M * 4);
    int*      colidx= (int*)     (p + off); off += roundup256((size_t)E * 4);
    (void)ws_size;

    // --- graph/degree prep ---
    dagnn_zero2<<<(M + 255) / 256, 256, 0, stream>>>(degi, fillc, M);
    dagnn_deg<<<(E + 255) / 256, 256, 0, stream>>>(dst, degi, E);
    dagnn_norm<<<(M + 255) / 256, 256, 0, stream>>>(degi, nrm, M);
    dagnn_scan<<<1, 1024, 0, stream>>>(degi, rowptr, M);
    dagnn_fill<<<(E + 255) / 256, 256, 0, stream>>>(src, dst, rowptr, fillc, colidx, E);

    // --- weight prep ---
    dagnn_w1t<<<(HID * KPAD + 255) / 256, 256, 0, stream>>>(W1, W1t);
    dagnn_w2t<<<(CPAD * HID + 255) / 256, 256, 0, stream>>>(W2, W2t);
    dagnn_sgate4<<<1, 64, 0, stream>>>(svec, sg4);

    // --- MLP ---
    dim3 g1((M + 127) / 128, 2);
    dagnn_gemm1_mfma<<<g1, 256, 0, stream>>>(feats, W1t, b1, hid, M);
    dagnn_mlp2_mfma<<<(M + 127) / 128, 256, 0, stream>>>(hid, W2t, b2, svec, nrm,
                                                         hsA, out, M);

    // --- K propagation hops with online output accumulation ---
    unsigned* hin = hsA;
    unsigned* hout = hsB;
    for (int k = 0; k < KHOPS; ++k) {
        dagnn_prop5<<<(M + 3) / 4, 256, 0, stream>>>(hin, nrm, rowptr, colidx,
                                                     sg4, hout, out, M,
                                                     k < KHOPS - 1);
        unsigned* t = hin; hin = hout; hout = t;
    }
}